// Round 1
// baseline (47.048 us; speedup 1.0000x reference)
//
#include <hip/hip_runtime.h>

// ZNCC 5x5, zero-padded, count_include_pad means.
// x,y: (4,3,512,512) f32 -> out: (4,1,512,512) f32
// out(b,h,w) = mean_c clip( mean_{25}( (ax*ay+c) * rsqrt((ax^2+c)*(ay^2+c)) ), 0, 1 )
// ax = |x[h+i-2,w+j-2] - mean5x5(x)(h,w)|  (OOB -> 0)

constexpr int W  = 512, H = 512, C = 3, B = 4;
constexpr int TW = 64, TH = 16, HALO = 2;
constexpr int LW = TW + 2 * HALO;   // 68 (stride mult of 4 -> float4 alignment kept)
constexpr int LH = TH + 2 * HALO;   // 20

__global__ __launch_bounds__(256, 4)
void zncc_kernel(const float* __restrict__ x,
                 const float* __restrict__ y,
                 float* __restrict__ out) {
    __shared__ float sx[LH][LW];
    __shared__ float sy[LH][LW];

    const int tid = threadIdx.x;
    const int tx  = tid & 15;    // 16 thread-cols x 4 px = 64 cols
    const int ty  = tid >> 4;    // 16 rows
    const int w0  = blockIdx.x * TW;
    const int h0  = blockIdx.y * TH;
    const int b   = blockIdx.z;

    const float EPS = 1e-4f;
    float chan_acc[4] = {0.f, 0.f, 0.f, 0.f};

    for (int c = 0; c < C; ++c) {
        const float* __restrict__ xb = x + (size_t)(b * C + c) * (H * W);
        const float* __restrict__ yb = y + (size_t)(b * C + c) * (H * W);

        // ---- stage zero-padded 20x68 tiles ----
        for (int i = tid; i < LH * LW; i += 256) {
            const int l  = i / LW;
            const int m  = i - l * LW;
            const int gr = h0 + l - HALO;
            const int gc = w0 + m - HALO;
            const bool ok = ((unsigned)gr < (unsigned)H) && ((unsigned)gc < (unsigned)W);
            const int gi = gr * W + gc;
            sx[l][m] = ok ? xb[gi] : 0.f;
            sy[l][m] = ok ? yb[gi] : 0.f;
        }
        __syncthreads();

        // ---- pass A: 5x5 means for my 4 pixels (sliding row sums) ----
        float sxs[4] = {0.f, 0.f, 0.f, 0.f};
        float sys[4] = {0.f, 0.f, 0.f, 0.f};
        #pragma unroll
        for (int r = 0; r < 5; ++r) {
            const float4 a0 = *reinterpret_cast<const float4*>(&sx[ty + r][4 * tx]);
            const float4 a1 = *reinterpret_cast<const float4*>(&sx[ty + r][4 * tx + 4]);
            const float4 b0 = *reinterpret_cast<const float4*>(&sy[ty + r][4 * tx]);
            const float4 b1 = *reinterpret_cast<const float4*>(&sy[ty + r][4 * tx + 4]);
            const float rx[8] = {a0.x, a0.y, a0.z, a0.w, a1.x, a1.y, a1.z, a1.w};
            const float ry[8] = {b0.x, b0.y, b0.z, b0.w, b1.x, b1.y, b1.z, b1.w};
            float s = rx[0] + rx[1] + rx[2] + rx[3] + rx[4];
            sxs[0] += s; s += rx[5] - rx[0];
            sxs[1] += s; s += rx[6] - rx[1];
            sxs[2] += s; s += rx[7] - rx[2];
            sxs[3] += s;
            float t = ry[0] + ry[1] + ry[2] + ry[3] + ry[4];
            sys[0] += t; t += ry[5] - ry[0];
            sys[1] += t; t += ry[6] - ry[1];
            sys[2] += t; t += ry[7] - ry[2];
            sys[3] += t;
        }
        float mx[4], my[4];
        #pragma unroll
        for (int p = 0; p < 4; ++p) {
            mx[p] = sxs[p] * (1.f / 25.f);
            my[p] = sys[p] * (1.f / 25.f);
        }

        // ---- pass B: ncc accumulation ----
        float acc[4] = {0.f, 0.f, 0.f, 0.f};
        #pragma unroll
        for (int r = 0; r < 5; ++r) {
            const float4 a0 = *reinterpret_cast<const float4*>(&sx[ty + r][4 * tx]);
            const float4 a1 = *reinterpret_cast<const float4*>(&sx[ty + r][4 * tx + 4]);
            const float4 b0 = *reinterpret_cast<const float4*>(&sy[ty + r][4 * tx]);
            const float4 b1 = *reinterpret_cast<const float4*>(&sy[ty + r][4 * tx + 4]);
            const float rx[8] = {a0.x, a0.y, a0.z, a0.w, a1.x, a1.y, a1.z, a1.w};
            const float ry[8] = {b0.x, b0.y, b0.z, b0.w, b1.x, b1.y, b1.z, b1.w};
            #pragma unroll
            for (int p = 0; p < 4; ++p) {
                #pragma unroll
                for (int j = 0; j < 5; ++j) {
                    const float ax  = fabsf(rx[p + j] - mx[p]);
                    const float ay  = fabsf(ry[p + j] - my[p]);
                    const float num = ax * ay + EPS;
                    const float den = (ax * ax + EPS) * (ay * ay + EPS);
                    acc[p] += num * __builtin_amdgcn_rsqf(den);
                }
            }
        }
        #pragma unroll
        for (int p = 0; p < 4; ++p) {
            float v = acc[p] * (1.f / 25.f);
            v = fminf(fmaxf(v, 0.f), 1.f);
            chan_acc[p] += v;
        }
        __syncthreads();   // protect LDS before next channel's staging
    }

    const int orow = h0 + ty;
    float4 o;
    o.x = chan_acc[0] * (1.f / 3.f);
    o.y = chan_acc[1] * (1.f / 3.f);
    o.z = chan_acc[2] * (1.f / 3.f);
    o.w = chan_acc[3] * (1.f / 3.f);
    *reinterpret_cast<float4*>(&out[((size_t)b * H + orow) * W + w0 + 4 * tx]) = o;
}

extern "C" void kernel_launch(void* const* d_in, const int* in_sizes, int n_in,
                              void* d_out, int out_size, void* d_ws, size_t ws_size,
                              hipStream_t stream) {
    const float* x = (const float*)d_in[0];
    const float* y = (const float*)d_in[1];
    float* out = (float*)d_out;
    dim3 grid(W / TW, H / TH, B);   // 8, 32, 4 = 1024 blocks (4 per CU)
    zncc_kernel<<<grid, dim3(256), 0, stream>>>(x, y, out);
}